// Round 5
// baseline (9.718 us; speedup 1.0000x reference)
//
#include <hip/hip_runtime.h>
#include <math.h>

#define R_SIZE 4096
#define B_SIZE 65536
#define NN 8                      // Chebyshev nodes -> degree-7 interpolant
#define LOG2E 1.4426950408889634f

__device__ __forceinline__ float fast_exp2(float v) {
#if __has_builtin(__builtin_amdgcn_exp2f)
    return __builtin_amdgcn_exp2f(v);
#else
    return exp2f(v);
#endif
}

// Single fused kernel, one WG per CU (grid 256 x 256 thr).
//  1) issue ALL global loads up front (x + this thread's 16 refs),
//  2) run the serial tanh MLP (depends only on x, the first load) while the
//     ref loads are still in flight -- hides the ~400-cyc dependent chain,
//  3) accumulate gt(f_k) = sum_j w_cls_j * 2^(f_k*p_j - q_j) at the 8
//     Chebyshev nodes from the preloaded registers,
//  4) butterfly + LDS reduce, 8x8 DCT -> Chebyshev coeffs, Clenshaw at f,
//     apply Gaussian prefactor 2^(-2 f^2 log2e), add b_cls.
// Interp error ~1e-8 << 1.8e-3 threshold (verified absmax 0.0 in R4).
__global__ __launch_bounds__(256) void fraud_fused_kernel(
    const float* __restrict__ x,
    const float* __restrict__ w0, const float* __restrict__ b0,
    const float* __restrict__ wl, const float* __restrict__ bl,
    const float* __restrict__ w_out, const float* __restrict__ b_out,
    const float* __restrict__ ref_feats, const float* __restrict__ w_cls,
    const float* __restrict__ b_cls,
    float* __restrict__ out)
{
    const int tid  = threadIdx.x;
    const int lane = tid & 63;
    const int wid  = tid >> 6;
    const int i    = blockIdx.x * 256 + tid;

    // ---- issue every global load before any compute ----
    const float2 xv = ((const float2*)x)[i];
    float4 y[8];
    float2 wv[8];
    #pragma unroll
    for (int m = 0; m < 8; ++m) {
        y[m]  = ((const float4*)ref_feats)[tid + m * 256];   // refs 2j2, 2j2+1
        wv[m] = ((const float2*)w_cls)[tid + m * 256];
    }

    // ---- tiny MLP backbone -> scalar f (runs while ref loads land) ----
    float h0 = tanhf(w0[0] * xv.x + w0[1] * xv.y + b0[0]) * 0.1f;
    float h1 = tanhf(w0[2] * xv.x + w0[3] * xv.y + b0[1]) * 0.1f;
    #pragma unroll
    for (int l = 0; l < 3; ++l) {
        const float* W  = wl + 4 * l;
        const float* Bv = bl + 2 * l;
        const float t0 = tanhf(W[0] * h0 + W[1] * h1 + Bv[0]) * 0.05f;
        const float t1 = tanhf(W[2] * h0 + W[3] * h1 + Bv[1]) * 0.05f;
        h0 = t0; h1 = t1;
    }
    const float wo0 = w_out[0], wo1 = w_out[1], bo = b_out[0];
    const float f = wo0 * h0 + wo1 * h1 + bo;
    const float scale = fast_exp2(-2.0f * f * f * LOG2E);

    // f-range: |h_d| < 0.05 strictly -> f in bo +- hs, so u = (f-bo)/hs in (-1,1)
    float hs = 0.05f * (fabsf(wo0) + fabsf(wo1));
    hs = fmaxf(hs, 5e-7f);

    // Chebyshev nodes u_k = cos(pi(k+1/2)/8)
    const float U[NN] = { 0.980785280f,  0.831469612f,  0.555570233f,  0.195090322f,
                         -0.195090322f, -0.555570233f, -0.831469612f, -0.980785281f};
    float fk[NN];
    #pragma unroll
    for (int k = 0; k < NN; ++k) fk[k] = bo + hs * U[k];

    // ---- node sums over this thread's 16 refs (preloaded) ----
    float acc[NN] = {0.f,0.f,0.f,0.f,0.f,0.f,0.f,0.f};
    #pragma unroll
    for (int m = 0; m < 8; ++m) {
        const float p0 = 2.0f * LOG2E * (y[m].x + y[m].y);
        const float q0 = LOG2E * (y[m].x * y[m].x + y[m].y * y[m].y);
        const float p1 = 2.0f * LOG2E * (y[m].z + y[m].w);
        const float q1 = LOG2E * (y[m].z * y[m].z + y[m].w * y[m].w);
        #pragma unroll
        for (int k = 0; k < NN; ++k) {
            acc[k] += wv[m].x * fast_exp2(fk[k] * p0 - q0);
            acc[k] += wv[m].y * fast_exp2(fk[k] * p1 - q1);
        }
    }

    // ---- wave64 butterfly reduce each node sum ----
    #pragma unroll
    for (int k = 0; k < NN; ++k) {
        float v = acc[k];
        #pragma unroll
        for (int off = 32; off; off >>= 1) v += __shfl_xor(v, off);
        acc[k] = v;
    }

    __shared__ float s_red[4][NN];
    if (lane == 0) {
        #pragma unroll
        for (int k = 0; k < NN; ++k) s_red[wid][k] = acc[k];
    }
    __syncthreads();

    float g[NN];
    #pragma unroll
    for (int k = 0; k < NN; ++k)
        g[k] = (s_red[0][k] + s_red[1][k]) + (s_red[2][k] + s_red[3][k]);

    // ---- DCT-II projection -> Chebyshev coefficients (constant 8x8) ----
    const float M[7][NN] = {
      { 0.980785280f,  0.831469612f,  0.555570233f,  0.195090322f, -0.195090322f, -0.555570233f, -0.831469612f, -0.980785281f},
      { 0.923879533f,  0.382683432f, -0.382683432f, -0.923879533f, -0.923879533f, -0.382683432f,  0.382683432f,  0.923879533f},
      { 0.831469612f, -0.195090322f, -0.980785281f, -0.555570233f,  0.555570233f,  0.980785281f,  0.195090322f, -0.831469612f},
      { 0.707106781f, -0.707106781f, -0.707106781f,  0.707106781f,  0.707106781f, -0.707106781f, -0.707106781f,  0.707106781f},
      { 0.555570233f, -0.980785281f,  0.195090322f,  0.831469612f, -0.831469612f, -0.195090322f,  0.980785281f, -0.555570233f},
      { 0.382683432f, -0.923879533f,  0.923879533f, -0.382683432f, -0.382683432f,  0.923879533f, -0.923879533f,  0.382683432f},
      { 0.195090322f, -0.555570233f,  0.831469612f, -0.980785281f,  0.980785281f, -0.831469612f,  0.555570233f, -0.195090322f}};
    float c[NN];
    c[0] = 0.125f * (((g[0] + g[1]) + (g[2] + g[3])) + ((g[4] + g[5]) + (g[6] + g[7])));
    #pragma unroll
    for (int n = 1; n < NN; ++n) {
        float s = 0.f;
        #pragma unroll
        for (int k = 0; k < NN; ++k) s += M[n - 1][k] * g[k];
        c[n] = 0.25f * s;
    }

    // ---- Clenshaw at u = (f - bo)/hs, then Gaussian prefactor ----
    const float u  = (f - bo) / hs;
    const float tu = 2.0f * u;
    float b1 = 0.f, b2 = 0.f;
    #pragma unroll
    for (int n = 7; n >= 1; --n) {
        const float t = tu * b1 - b2 + c[n];
        b2 = b1; b1 = t;
    }
    const float gt = u * b1 - b2 + c[0];

    out[i] = scale * gt + b_cls[0];
}

extern "C" void kernel_launch(void* const* d_in, const int* in_sizes, int n_in,
                              void* d_out, int out_size, void* d_ws, size_t ws_size,
                              hipStream_t stream) {
    const float* x      = (const float*)d_in[0];
    const float* w0     = (const float*)d_in[1];
    const float* b0     = (const float*)d_in[2];
    const float* wl     = (const float*)d_in[3];
    const float* bl     = (const float*)d_in[4];
    const float* w_out  = (const float*)d_in[5];
    const float* b_out  = (const float*)d_in[6];
    const float* ref    = (const float*)d_in[7];
    const float* w_cls  = (const float*)d_in[8];
    const float* b_cls  = (const float*)d_in[9];
    float* out = (float*)d_out;

    fraud_fused_kernel<<<B_SIZE / 256, 256, 0, stream>>>(
        x, w0, b0, wl, bl, w_out, b_out, ref, w_cls, b_cls, out);
}